// Round 1
// baseline (15561.760 us; speedup 1.0000x reference)
//
#include <hip/hip_runtime.h>
#include <hip/hip_bf16.h>
#include <stdint.h>

#define HW2 262144            // 512*512
#define GHN 17
#define NBLK 1156             // 4*17*17

// ---------- storage-type helpers (fp32 tier or bf16 fallback tier) ----------
struct BF16 { unsigned short v; };

__device__ inline float b2f(unsigned short u){ return __uint_as_float(((unsigned)u)<<16); }
__device__ inline unsigned short f2b(float f){
  unsigned x = __float_as_uint(f);
  return (unsigned short)((x + 0x7fffu + ((x>>16)&1u)) >> 16);
}
__device__ inline float ld1(const float* p){ return *p; }
__device__ inline float ld1(const BF16* p){ return b2f(p->v); }
__device__ inline float4 ld4(const float* p){ return *(const float4*)p; }
__device__ inline float4 ld4(const BF16* p){
  ushort4 u = *(const ushort4*)p;
  return make_float4(b2f(u.x), b2f(u.y), b2f(u.z), b2f(u.w));
}
__device__ inline void st4(float* p, float4 v){ *(float4*)p = v; }
__device__ inline void st4(BF16* p, float4 v){
  *(ushort4*)p = make_ushort4(f2b(v.x), f2b(v.y), f2b(v.z), f2b(v.w));
}

// ---------- K0: active-block flags + compaction ----------
__global__ void k_flags(const int* __restrict__ mask, int* __restrict__ slotmap,
                        int* __restrict__ list, int* __restrict__ count){
  int b = blockIdx.x;
  int n = b/(GHN*GHN); int r = b - n*(GHN*GHN); int gh = r/GHN, gw = r - gh*GHN;
  int y0 = gh*32-16, x0 = gw*32-16;
  int s = 0;
  for (int i = threadIdx.x; i < 1024; i += 256){
    int y = y0 + (i>>5), x = x0 + (i&31);
    if ((unsigned)y < 512u && (unsigned)x < 512u)
      s += mask[((size_t)n<<18) + (y<<9) + x];
  }
  for (int o=32;o;o>>=1) s += __shfl_down(s,o,64);
  __shared__ int red[4];
  if ((threadIdx.x&63)==0) red[threadIdx.x>>6] = s;
  __syncthreads();
  if (threadIdx.x==0){
    int tot = red[0]+red[1]+red[2]+red[3];
    int slot = -1;
    if (tot >= 205){ slot = atomicAdd(count,1); list[slot] = b; }   // mean>0.2 <=> sum>=205
    slotmap[b] = slot;
  }
}

// ---------- K1: channel_control conv1x1(64->64) + bias + relu -> t, stats ----------
__global__ __launch_bounds__(256) void k_cc(const float* __restrict__ x,
    const float* __restrict__ w, const float* __restrict__ bias,
    float* __restrict__ t, double* __restrict__ st){
  __shared__ float wl[64*64];                    // [ci][co]
  for (int i = threadIdx.x; i < 4096; i += 256){
    int ci = i>>6, co = i&63;
    wl[i] = w[co*64+ci];
  }
  __syncthreads();
  int wg = blockIdx.x;                           // 4096 wgs
  int n = wg>>10, chunk = wg&1023;
  int cog = threadIdx.x>>6;                      // wave id = co-group (16 co)
  int pxg = threadIdx.x&63;
  int px = chunk*256 + pxg*4;
  const float* xp = x + ((size_t)n<<24) + px;
  float4 acc[16];
  #pragma unroll
  for (int k=0;k<16;k++) acc[k]=make_float4(0.f,0.f,0.f,0.f);
  for (int ci=0; ci<64; ci++){
    float4 xv = *(const float4*)(xp + (size_t)ci*HW2);
    const float* wr = &wl[ci*64 + cog*16];
    #pragma unroll
    for (int k=0;k<16;k++){
      float wv = wr[k];
      acc[k].x += wv*xv.x; acc[k].y += wv*xv.y; acc[k].z += wv*xv.z; acc[k].w += wv*xv.w;
    }
  }
  float* tp = t + ((size_t)n<<24) + px;
  float s1[16], s2[16];
  #pragma unroll
  for (int k=0;k<16;k++){
    int co = cog*16+k;
    float bb = bias[co];
    float4 v = acc[k];
    v.x=fmaxf(v.x+bb,0.f); v.y=fmaxf(v.y+bb,0.f); v.z=fmaxf(v.z+bb,0.f); v.w=fmaxf(v.w+bb,0.f);
    *(float4*)(tp + (size_t)co*HW2) = v;
    s1[k]=v.x+v.y+v.z+v.w; s2[k]=v.x*v.x+v.y*v.y+v.z*v.z+v.w*v.w;
  }
  #pragma unroll
  for (int k=0;k<16;k++){
    float a=s1[k], c2=s2[k];
    for (int o=32;o;o>>=1){ a += __shfl_down(a,o,64); c2 += __shfl_down(c2,o,64); }
    if (pxg==0){
      int co = cog*16+k;
      atomicAdd(&st[co],   (double)a);
      atomicAdd(&st[64+co],(double)c2);
    }
  }
}

// ---------- finalize BN: scale/shift from (sum, sumsq) ----------
__global__ void k_fin(const double* __restrict__ st, const float* __restrict__ gamma,
                      const float* __restrict__ beta, float* __restrict__ sc,
                      float* __restrict__ sh, int C, const int* __restrict__ cnt, int fixedCnt){
  int c = threadIdx.x;
  if (c >= C) return;
  double n = fixedCnt ? (double)fixedCnt : (double)(*cnt) * 1024.0;
  double mean = st[c]/n;
  double var  = st[C+c]/n - mean*mean;
  double isd  = 1.0 / sqrt(var + 1e-5);
  sc[c] = (float)((double)gamma[c] * isd);
  sh[c] = (float)((double)beta[c] - mean * (double)gamma[c] * isd);
}

// ---------- K3: gather + bn0 + conv1x1(64->128) + relu -> u1, stats ----------
template<typename TS>
__global__ __launch_bounds__(256) void k_conv1(const float* __restrict__ t,
    const float* __restrict__ w1, const float* __restrict__ b1,
    const float* __restrict__ sc0, const float* __restrict__ sh0,
    TS* __restrict__ u1, double* __restrict__ st,
    const int* __restrict__ list, const int* __restrict__ count){
  int wg = blockIdx.x;
  int sblk = wg>>3, chunk = wg&7;
  if (sblk >= *count) return;
  int b = list[sblk];
  int n = b/(GHN*GHN); int r = b - n*(GHN*GHN); int gh = r/GHN, gw = r - gh*GHN;
  __shared__ float wl[64*128];                  // [ci][co]
  for (int i=threadIdx.x; i<8192; i+=256){
    int ci = i>>7, co = i&127;
    wl[i] = w1[co*64+ci];
  }
  __syncthreads();
  int cog = threadIdx.x>>5;                     // 0..7 -> 16 co each
  int pxg = threadIdx.x&31;
  int px = chunk*128 + pxg*4;
  int kh = px>>5, kw = px&31;
  int oh = gh*32-16+kh, ow = gw*32-16+kw;
  bool inb = ((unsigned)oh<512u) && ((unsigned)ow<512u);
  const float* tp = t + ((size_t)n<<24) + oh*512 + ow;
  float4 acc[16];
  #pragma unroll
  for (int k=0;k<16;k++) acc[k]=make_float4(0.f,0.f,0.f,0.f);
  for (int ci=0; ci<64; ci++){
    float4 v;
    if (inb){
      v = *(const float4*)(tp + (size_t)ci*HW2);
      float s = sc0[ci], h = sh0[ci];
      v.x=s*v.x+h; v.y=s*v.y+h; v.z=s*v.z+h; v.w=s*v.w+h;
    } else v = make_float4(0.f,0.f,0.f,0.f);
    const float* wr = &wl[ci*128 + cog*16];
    #pragma unroll
    for (int k=0;k<16;k++){
      float wv = wr[k];
      acc[k].x += wv*v.x; acc[k].y += wv*v.y; acc[k].z += wv*v.z; acc[k].w += wv*v.w;
    }
  }
  TS* up = u1 + ((size_t)sblk*128)*1024 + px;
  float s1[16], s2[16];
  #pragma unroll
  for (int k=0;k<16;k++){
    int co = cog*16+k;
    float bb = b1[co];
    float4 v = acc[k];
    v.x=fmaxf(v.x+bb,0.f); v.y=fmaxf(v.y+bb,0.f); v.z=fmaxf(v.z+bb,0.f); v.w=fmaxf(v.w+bb,0.f);
    st4(up + (size_t)co*1024, v);
    s1[k]=v.x+v.y+v.z+v.w; s2[k]=v.x*v.x+v.y*v.y+v.z*v.z+v.w*v.w;
  }
  #pragma unroll
  for (int k=0;k<16;k++){
    float a=s1[k], c2=s2[k];
    for (int o=16;o;o>>=1){ a += __shfl_xor(a,o,64); c2 += __shfl_xor(c2,o,64); }
    if (pxg==0){
      int co = cog*16+k;
      atomicAdd(&st[co],    (double)a);
      atomicAdd(&st[128+co],(double)c2);
    }
  }
}

// ---------- K5: bn1 + conv3x3(128->128, pad1 per block) + relu -> u2, stats ----------
template<typename TS>
__global__ __launch_bounds__(256) void k_conv3(const TS* __restrict__ u1,
    const float* __restrict__ w2, const float* __restrict__ b2,
    const float* __restrict__ sc1, const float* __restrict__ sh1,
    TS* __restrict__ u2, double* __restrict__ st,
    const int* __restrict__ list, const int* __restrict__ count){
  int wg = blockIdx.x;
  int sblk = wg>>3;
  if (sblk >= *count) return;
  int cot = (wg>>1)&3, half = wg&1;            // co-tile of 32, row half of 16
  __shared__ float tile[2][4][18][36];         // [buf][ci][row(-1..16)][col(-1..33pad)]
  __shared__ float wl[2][4][32][9];
  const int t0 = threadIdx.x;
  // zero column halos (cols 0 and 33); rows fully re-staged each iteration
  for (int i=t0; i<144; i+=256){
    int bu = i/72, rest = i-bu*72;
    int ci = rest/18, lr = rest-ci*18;
    tile[bu][ci][lr][0] = 0.f;
    tile[bu][ci][lr][33] = 0.f;
  }
  int cog = t0>>6;                              // wave id, 8 co each
  int rr = t0&63; int row_l = rr>>2; int x0 = (rr&3)*8;
  float acc[8][8];
  #pragma unroll
  for (int k=0;k<8;k++)
    #pragma unroll
    for (int xx=0;xx<8;xx++) acc[k][xx]=0.f;

  float pv[9], pw[5];
  auto ldstage = [&](int cg){
    #pragma unroll
    for (int j=0;j<9;j++){
      int i = t0 + j*256;
      int ci_l = i/576, rem = i - ci_l*576;
      int lr = rem>>5, cc = rem&31;
      int grow = half*16 - 1 + lr;
      int ci = cg*4 + ci_l;
      float v = 0.f;
      if ((unsigned)grow < 32u)
        v = sc1[ci]*ld1(u1 + ((size_t)sblk*128 + ci)*1024 + grow*32 + cc) + sh1[ci];
      pv[j] = v;
    }
    #pragma unroll
    for (int j=0;j<5;j++){
      int i = t0 + j*256;
      if (i < 1152){
        int ci_l = i/288, rem = i - ci_l*288;
        int co_l = rem/9, k = rem - co_l*9;
        pw[j] = w2[(((size_t)(cot*32+co_l))*128 + (cg*4+ci_l))*9 + k];
      }
    }
  };
  auto wrstage = [&](int buf){
    #pragma unroll
    for (int j=0;j<9;j++){
      int i = t0 + j*256;
      int ci_l = i/576, rem = i - ci_l*576;
      int lr = rem>>5, cc = rem&31;
      tile[buf][ci_l][lr][1+cc] = pv[j];
    }
    #pragma unroll
    for (int j=0;j<5;j++){
      int i = t0 + j*256;
      if (i<1152){
        int ci_l = i/288, rem = i - ci_l*288;
        int co_l = rem/9, k = rem - co_l*9;
        wl[buf][ci_l][co_l][k] = pw[j];
      }
    }
  };

  ldstage(0);
  wrstage(0);
  __syncthreads();
  for (int cg=0; cg<32; cg++){
    int buf = cg&1;
    if (cg<31) ldstage(cg+1);                   // global loads overlap compute
    #pragma unroll
    for (int ci_l=0; ci_l<4; ci_l++){
      float in[3][10];
      #pragma unroll
      for (int dy=0;dy<3;dy++)
        #pragma unroll
        for (int dx=0;dx<10;dx++)
          in[dy][dx] = tile[buf][ci_l][row_l+dy][x0+dx];
      #pragma unroll
      for (int k=0;k<8;k++){
        const float* wp = wl[buf][ci_l][cog*8+k];
        float w00=wp[0],w01=wp[1],w02=wp[2],w10=wp[3],w11=wp[4],w12=wp[5],w20=wp[6],w21=wp[7],w22=wp[8];
        #pragma unroll
        for (int xx=0;xx<8;xx++){
          float a = acc[k][xx];
          a += w00*in[0][xx]; a += w01*in[0][xx+1]; a += w02*in[0][xx+2];
          a += w10*in[1][xx]; a += w11*in[1][xx+1]; a += w12*in[1][xx+2];
          a += w20*in[2][xx]; a += w21*in[2][xx+1]; a += w22*in[2][xx+2];
          acc[k][xx] = a;
        }
      }
    }
    __syncthreads();
    if (cg<31) wrstage(buf^1);
    __syncthreads();
  }
  int row = half*16 + row_l;
  TS* up = u2 + ((size_t)sblk*128)*1024 + row*32 + x0;
  float s1a[8], s2a[8];
  #pragma unroll
  for (int k=0;k<8;k++){
    int co = cot*32 + cog*8 + k;
    float bb = b2[co];
    float a1=0.f, a2=0.f;
    #pragma unroll
    for (int xx=0;xx<8;xx++){
      float v = fmaxf(acc[k][xx]+bb, 0.f);
      acc[k][xx]=v; a1+=v; a2+=v*v;
    }
    st4(up + (size_t)co*1024,     make_float4(acc[k][0],acc[k][1],acc[k][2],acc[k][3]));
    st4(up + (size_t)co*1024 + 4, make_float4(acc[k][4],acc[k][5],acc[k][6],acc[k][7]));
    s1a[k]=a1; s2a[k]=a2;
  }
  #pragma unroll
  for (int k=0;k<8;k++){
    float a=s1a[k], c2=s2a[k];
    for (int o=32;o;o>>=1){ a+=__shfl_down(a,o,64); c2+=__shfl_down(c2,o,64); }
    if ((t0&63)==0){
      int co = cot*32 + cog*8 + k;
      atomicAdd(&st[co],    (double)a);
      atomicAdd(&st[128+co],(double)c2);
    }
  }
}

// ---------- K7: bn2 + conv1x1(128->64) + relu -> g, stats ----------
template<typename TS>
__global__ __launch_bounds__(256) void k_convD(const TS* __restrict__ u2,
    const float* __restrict__ w3, const float* __restrict__ b3,
    const float* __restrict__ sc2, const float* __restrict__ sh2,
    TS* __restrict__ g, double* __restrict__ st,
    const int* __restrict__ list, const int* __restrict__ count){
  int wg = blockIdx.x;
  int sblk = wg>>3, chunk = wg&7;
  if (sblk >= *count) return;
  __shared__ float wl[128*64];                  // [ci][co]
  for (int i=threadIdx.x;i<8192;i+=256){
    int ci=i>>6, co=i&63;
    wl[i] = w3[co*128+ci];
  }
  __syncthreads();
  int cog = threadIdx.x>>5;                     // 8 groups x 8 co
  int pxg = threadIdx.x&31;
  int px = chunk*128 + pxg*4;
  const TS* u2p = u2 + ((size_t)sblk*128)*1024 + px;
  float4 acc[8];
  #pragma unroll
  for (int k=0;k<8;k++) acc[k]=make_float4(0.f,0.f,0.f,0.f);
  for (int ci=0;ci<128;ci++){
    float4 v = ld4(u2p + (size_t)ci*1024);
    float s=sc2[ci], h=sh2[ci];
    v.x=s*v.x+h; v.y=s*v.y+h; v.z=s*v.z+h; v.w=s*v.w+h;
    const float* wr=&wl[ci*64+cog*8];
    #pragma unroll
    for (int k=0;k<8;k++){
      float wv=wr[k];
      acc[k].x += wv*v.x; acc[k].y += wv*v.y; acc[k].z += wv*v.z; acc[k].w += wv*v.w;
    }
  }
  TS* gp = g + ((size_t)sblk*64)*1024 + px;
  float s1[8], s2[8];
  #pragma unroll
  for (int k=0;k<8;k++){
    int co = cog*8+k;
    float bb = b3[co];
    float4 v = acc[k];
    v.x=fmaxf(v.x+bb,0.f); v.y=fmaxf(v.y+bb,0.f); v.z=fmaxf(v.z+bb,0.f); v.w=fmaxf(v.w+bb,0.f);
    st4(gp + (size_t)co*1024, v);
    s1[k]=v.x+v.y+v.z+v.w; s2[k]=v.x*v.x+v.y*v.y+v.z*v.z+v.w*v.w;
  }
  #pragma unroll
  for (int k=0;k<8;k++){
    float a=s1[k], c2=s2[k];
    for (int o=16;o;o>>=1){ a+=__shfl_xor(a,o,64); c2+=__shfl_xor(c2,o,64); }
    if (pxg==0){
      int co = cog*8+k;
      atomicAdd(&st[co],   (double)a);
      atomicAdd(&st[64+co],(double)c2);
    }
  }
}

// ---------- K9: final output = pad(bn0(t)) + scatter(bn3(g)) ----------
template<typename TS>
__global__ __launch_bounds__(256) void k_out(const float* __restrict__ t,
    const TS* __restrict__ g, const float* __restrict__ sc0, const float* __restrict__ sh0,
    const float* __restrict__ sc3, const float* __restrict__ sh3,
    const int* __restrict__ slotmap, float* __restrict__ out){
  int i = blockIdx.x*256 + threadIdx.x;        // 0..73983 (float4s per image plane)
  if (i >= 73984) return;
  int nc = blockIdx.y;                          // 0..255 = n*64+c
  int n = nc>>6, c = nc&63;
  int ph = i/136; int pw = (i - ph*136)*4;
  float4 v = make_float4(0.f,0.f,0.f,0.f);
  int oh = ph-16, ow = pw-16;
  if ((unsigned)oh<512u && pw>=16 && pw<528){
    float4 tv = *(const float4*)(t + ((size_t)n<<24) + (size_t)c*HW2 + oh*512 + ow);
    float s=sc0[c], h=sh0[c];
    v = make_float4(s*tv.x+h, s*tv.y+h, s*tv.z+h, s*tv.w+h);
  }
  int gh_=ph>>5, gw_=pw>>5;
  int slot = slotmap[n*289 + gh_*17 + gw_];
  if (slot>=0){
    int kh=ph&31, kw=pw&31;
    float4 gv = ld4(g + ((size_t)slot*64 + c)*1024 + kh*32 + kw);
    float s=sc3[c], h=sh3[c];
    v.x += s*gv.x+h; v.y += s*gv.y+h; v.z += s*gv.z+h; v.w += s*gv.w+h;
  }
  *(float4*)(out + ((size_t)nc)*295936 + (size_t)ph*544 + pw) = v;
}

// ---------- launch ----------
extern "C" void kernel_launch(void* const* d_in, const int* in_sizes, int n_in,
                              void* d_out, int out_size, void* d_ws, size_t ws_size,
                              hipStream_t stream){
  const float* x     = (const float*)d_in[0];
  const int*   mask  = (const int*)  d_in[1];
  const float* cc_w  = (const float*)d_in[2];
  const float* cc_b  = (const float*)d_in[3];
  const float* cc_g  = (const float*)d_in[4];
  const float* cc_be = (const float*)d_in[5];
  const float* w1 = (const float*)d_in[6];
  const float* b1 = (const float*)d_in[7];
  const float* g1 = (const float*)d_in[8];
  const float* be1= (const float*)d_in[9];
  const float* w2 = (const float*)d_in[10];
  const float* b2 = (const float*)d_in[11];
  const float* g2 = (const float*)d_in[12];
  const float* be2= (const float*)d_in[13];
  const float* w3 = (const float*)d_in[14];
  const float* b3 = (const float*)d_in[15];
  const float* g3 = (const float*)d_in[16];
  const float* be3= (const float*)d_in[17];
  float* out = (float*)d_out;

  char* ws = (char*)d_ws;
  int* count   = (int*)(ws + 0);
  int* slotmap = (int*)(ws + 64);
  int* list    = (int*)(ws + 4736);
  double* st0  = (double*)(ws + 9472);
  double* st1s = (double*)(ws + 10496);
  double* st2s = (double*)(ws + 12544);
  double* st3s = (double*)(ws + 14592);
  float* sc0=(float*)(ws+15616); float* sh0=(float*)(ws+15872);
  float* sc1=(float*)(ws+16128); float* sh1=(float*)(ws+16640);
  float* sc2=(float*)(ws+17152); float* sh2=(float*)(ws+17664);
  float* sc3=(float*)(ws+18176); float* sh3=(float*)(ws+18432);

  float* tbuf = (float*)(ws + 32768);
  const size_t T_BYTES = (size_t)4*64*262144*4;          // 268,435,456
  const size_t U32 = (size_t)NBLK*128*1024*4;            // 606,076,928
  size_t uoff = 32768 + T_BYTES;
  bool fp32tier = ws_size >= 32768 + T_BYTES + 2*U32;

  hipMemsetAsync(d_ws, 0, 32768, stream);
  k_flags<<<NBLK,256,0,stream>>>(mask, slotmap, list, count);
  k_cc<<<4096,256,0,stream>>>(x, cc_w, cc_b, tbuf, st0);
  k_fin<<<1,128,0,stream>>>(st0, cc_g, cc_be, sc0, sh0, 64, count, 1048576);

  if (fp32tier){
    float* u1 = (float*)(ws + uoff);
    float* u2 = (float*)(ws + uoff + U32);
    float* gb = u1;  // g reuses u1's space (u1 dead after conv3)
    k_conv1<float><<<NBLK*8,256,0,stream>>>(tbuf, w1, b1, sc0, sh0, u1, st1s, list, count);
    k_fin<<<1,128,0,stream>>>(st1s, g1, be1, sc1, sh1, 128, count, 0);
    k_conv3<float><<<NBLK*8,256,0,stream>>>(u1, w2, b2, sc1, sh1, u2, st2s, list, count);
    k_fin<<<1,128,0,stream>>>(st2s, g2, be2, sc2, sh2, 128, count, 0);
    k_convD<float><<<NBLK*8,256,0,stream>>>(u2, w3, b3, sc2, sh2, gb, st3s, list, count);
    k_fin<<<1,128,0,stream>>>(st3s, g3, be3, sc3, sh3, 64, count, 0);
    k_out<float><<<dim3(289,256),256,0,stream>>>(tbuf, gb, sc0, sh0, sc3, sh3, slotmap, out);
  } else {
    BF16* u1 = (BF16*)(ws + uoff);
    BF16* u2 = (BF16*)(ws + uoff + U32/2);
    BF16* gb = u1;
    k_conv1<BF16><<<NBLK*8,256,0,stream>>>(tbuf, w1, b1, sc0, sh0, u1, st1s, list, count);
    k_fin<<<1,128,0,stream>>>(st1s, g1, be1, sc1, sh1, 128, count, 0);
    k_conv3<BF16><<<NBLK*8,256,0,stream>>>(u1, w2, b2, sc1, sh1, u2, st2s, list, count);
    k_fin<<<1,128,0,stream>>>(st2s, g2, be2, sc2, sh2, 128, count, 0);
    k_convD<BF16><<<NBLK*8,256,0,stream>>>(u2, w3, b3, sc2, sh2, gb, st3s, list, count);
    k_fin<<<1,128,0,stream>>>(st3s, g3, be3, sc3, sh3, 64, count, 0);
    k_out<BF16><<<dim3(289,256),256,0,stream>>>(tbuf, gb, sc0, sh0, sc3, sh3, slotmap, out);
  }
}

// Round 2
// 1522.002 us; speedup vs baseline: 10.2245x; 10.2245x over previous
//
#include <hip/hip_runtime.h>
#include <stdint.h>

#define HW2 262144
#define GHN 17
#define NBLK 1156
#define MAXB 1024
#define PSTRIDE 9472

typedef __attribute__((ext_vector_type(8))) short bf8v;
typedef __attribute__((ext_vector_type(4))) float f32x4;
typedef unsigned short u16;
typedef unsigned int u32;

__device__ __forceinline__ float b2f(u16 u){ return __uint_as_float(((u32)u)<<16); }
__device__ __forceinline__ u16 f2b(float f){
  u32 x = __float_as_uint(f);
  return (u16)((x + 0x7fffu + ((x>>16)&1u)) >> 16);
}
__device__ __forceinline__ u32 pack2(float lo, float hi){
  return ((u32)f2b(hi)<<16) | f2b(lo);
}
__device__ __forceinline__ void gl_lds16(const void* g, void* l){
  __builtin_amdgcn_global_load_lds((const __attribute__((address_space(1))) u32*)g,
                                   (__attribute__((address_space(3))) u32*)l, 16, 0, 0);
}
__device__ __forceinline__ int dcnt(const int* c){ int v = *c; return v > MAXB ? MAXB : v; }

// ---------- K0: active-block flags + compaction ----------
__global__ void k_flags(const int* __restrict__ mask, int* __restrict__ slotmap,
                        int* __restrict__ list, int* __restrict__ count){
  int b = blockIdx.x;
  int n = b/(GHN*GHN); int r = b - n*(GHN*GHN); int gh = r/GHN, gw = r - gh*GHN;
  int y0 = gh*32-16, x0 = gw*32-16;
  int s = 0;
  for (int i = threadIdx.x; i < 1024; i += 256){
    int y = y0 + (i>>5), x = x0 + (i&31);
    if ((unsigned)y < 512u && (unsigned)x < 512u)
      s += mask[((size_t)n<<18) + (y<<9) + x];
  }
  for (int o=32;o;o>>=1) s += __shfl_down(s,o,64);
  __shared__ int red[4];
  if ((threadIdx.x&63)==0) red[threadIdx.x>>6] = s;
  __syncthreads();
  if (threadIdx.x==0){
    int tot = red[0]+red[1]+red[2]+red[3];
    int slot = -1;
    if (tot >= 205){                       // mean>0.2 <=> sum>=205
      slot = atomicAdd(count,1);
      if (slot < MAXB) list[slot] = b; else slot = -1;
    }
    slotmap[b] = slot;
  }
}

// ---------- K1: channel_control conv1x1(64->64) + bias + relu -> t (channel-last), stats ----------
__global__ __launch_bounds__(256) void k_cc(const float* __restrict__ x,
    const float* __restrict__ w, const float* __restrict__ bias,
    float* __restrict__ t, float* __restrict__ partials){
  __shared__ float wl[64*64];                    // [ci][co]
  __shared__ float st_s[128];
  for (int i = threadIdx.x; i < 4096; i += 256){
    int ci = i>>6, co = i&63;
    wl[i] = w[co*64+ci];
  }
  if (threadIdx.x < 128) st_s[threadIdx.x] = 0.f;
  __syncthreads();
  int wg = blockIdx.x;                           // 4096 wgs
  int n = wg>>10, chunk = wg&1023;
  int cog = threadIdx.x>>6;                      // wave id = co-group (16 co)
  int pxg = threadIdx.x&63;
  int px = chunk*256 + pxg*4;
  const float* xp = x + ((size_t)n<<24) + px;
  float4 acc[16];
  #pragma unroll
  for (int k=0;k<16;k++) acc[k]=make_float4(0.f,0.f,0.f,0.f);
  for (int ci=0; ci<64; ci++){
    float4 xv = *(const float4*)(xp + (size_t)ci*HW2);
    const float* wr = &wl[ci*64 + cog*16];
    #pragma unroll
    for (int k=0;k<16;k++){
      float wv = wr[k];
      acc[k].x += wv*xv.x; acc[k].y += wv*xv.y; acc[k].z += wv*xv.z; acc[k].w += wv*xv.w;
    }
  }
  float rr[16][4]; float s1[16], s2[16];
  #pragma unroll
  for (int k=0;k<16;k++){
    float bb = bias[cog*16+k];
    float4 v = acc[k];
    float e0=fmaxf(v.x+bb,0.f), e1=fmaxf(v.y+bb,0.f), e2=fmaxf(v.z+bb,0.f), e3=fmaxf(v.w+bb,0.f);
    rr[k][0]=e0; rr[k][1]=e1; rr[k][2]=e2; rr[k][3]=e3;
    s1[k]=e0+e1+e2+e3; s2[k]=e0*e0+e1*e1+e2*e2+e3*e3;
  }
  #pragma unroll
  for (int p=0;p<4;p++){
    #pragma unroll
    for (int q=0;q<4;q++){
      float4 o = make_float4(rr[4*q][p], rr[4*q+1][p], rr[4*q+2][p], rr[4*q+3][p]);
      *(float4*)(t + ((size_t)n*HW2 + px + p)*64 + cog*16 + q*4) = o;
    }
  }
  #pragma unroll
  for (int k=0;k<16;k++){
    float a=s1[k], c2=s2[k];
    for (int o=32;o;o>>=1){ a += __shfl_down(a,o,64); c2 += __shfl_down(c2,o,64); }
    if (pxg==0){
      int co = cog*16+k;
      atomicAdd(&st_s[co], a);
      atomicAdd(&st_s[64+co], c2);
    }
  }
  __syncthreads();
  if (threadIdx.x < 128) partials[(size_t)threadIdx.x*PSTRIDE + wg] = st_s[threadIdx.x];
}

// ---------- stats reduce + BN scale/shift finalize ----------
__global__ void k_finR(const float* __restrict__ partials, const float* __restrict__ gamma,
                       const float* __restrict__ beta, float* __restrict__ sc,
                       float* __restrict__ sh, int C, const int* __restrict__ count, int mode){
  int c = blockIdx.x;
  int cnt = dcnt(count);
  int ncols = mode ? cnt*8 : 4096;
  double n = mode ? (double)cnt*1024.0 : 1048576.0;
  const float* pr = partials + (size_t)c*PSTRIDE;
  const float* qr = partials + (size_t)(C+c)*PSTRIDE;
  double s=0.0, q=0.0;
  for (int col=threadIdx.x; col<ncols; col+=256){ s += pr[col]; q += qr[col]; }
  for (int o=32;o;o>>=1){ s += __shfl_down(s,o,64); q += __shfl_down(q,o,64); }
  __shared__ double sm[8];
  if ((threadIdx.x&63)==0){ sm[threadIdx.x>>6]=s; sm[4+(threadIdx.x>>6)]=q; }
  __syncthreads();
  if (threadIdx.x==0 && n > 0.5){
    double S=sm[0]+sm[1]+sm[2]+sm[3], Q=sm[4]+sm[5]+sm[6]+sm[7];
    double mean=S/n, var=Q/n-mean*mean;
    double isd = 1.0/sqrt(var+1e-5);
    sc[c]=(float)((double)gamma[c]*isd);
    sh[c]=(float)((double)beta[c]-mean*(double)gamma[c]*isd);
  }
}

// ---------- weight prep: w2 [co][ci][tap] -> w2t bf16 [tap][co][ci] ----------
__global__ void k_w2prep(const float* __restrict__ w2, u16* __restrict__ w2t){
  int d = blockIdx.x*256 + threadIdx.x;
  if (d >= 147456) return;
  int tap = d>>14; int rem = d & 16383; int co = rem>>7; int ci = rem&127;
  w2t[d] = f2b(w2[(co*128+ci)*9 + tap]);
}

// ---------- weight prep: w3t[co][ci] = bf16(sc2[ci]*w3[co][ci]); bias3p fold ----------
__global__ void k_w3prep(const float* __restrict__ w3, const float* __restrict__ b3,
                         const float* __restrict__ sc2, const float* __restrict__ sh2,
                         u16* __restrict__ w3t, float* __restrict__ bias3p){
  int co = threadIdx.x;
  if (co >= 64) return;
  float bacc = b3[co];
  for (int ci=0; ci<128; ci++){
    float wv = w3[co*128+ci];
    w3t[co*128+ci] = f2b(sc2[ci]*wv);
    bacc += sh2[ci]*wv;
  }
  bias3p[co] = bacc;
}

// ---------- K3: gather + bn0 + conv1x1(64->128) MFMA + relu -> u1 [px][128] bf16, stats ----------
__global__ __launch_bounds__(256) void k_conv1(const float* __restrict__ t,
    const float* __restrict__ w1, const float* __restrict__ b1,
    const float* __restrict__ sc0, const float* __restrict__ sh0,
    u16* __restrict__ u1, float* __restrict__ partials,
    const int* __restrict__ list, const int* __restrict__ count){
  int wg = blockIdx.x;
  int sblk = wg>>3, sub = wg&7;
  if (sblk >= dcnt(count)) return;
  int b = list[sblk];
  int n = b/(GHN*GHN); int r = b - n*(GHN*GHN); int gh = r/GHN, gw = r - gh*GHN;
  int px0 = sub*128;
  __shared__ u16 Aw[1024*8];     // chunk (ks,co,kg): idx = ks*512+co*4+kg
  __shared__ u16 Bp[1024*8];     // chunk (ks,kg,px): idx = ks*512+kg*128+px
  __shared__ float st_s[256];
  int tid = threadIdx.x;
  if (tid < 256) st_s[tid] = 0.f;
  // stage weights w1 [128co][64ci] -> bf16
  #pragma unroll
  for (int i=0;i<4;i++){
    int idx = tid + i*256;
    int ks = idx>>9, co = (idx>>2)&127, kgc = idx&3;
    int ci = ks*32 + kgc*8;
    const float* wp = w1 + co*64 + ci;
    float4 a = *(const float4*)wp, bq = *(const float4*)(wp+4);
    uint4 wv;
    wv.x = pack2(a.x,a.y); wv.y = pack2(a.z,a.w); wv.z = pack2(bq.x,bq.y); wv.w = pack2(bq.z,bq.w);
    *(uint4*)&Aw[idx*8] = wv;
  }
  // stage pixels: bn0(t) gathered, zero OOB
  #pragma unroll
  for (int i=0;i<4;i++){
    int idx = tid + i*256;
    int ks = idx>>9, kgc = (idx>>7)&3, px = idx&127;
    int bpx = px0 + px;
    int kh = bpx>>5, kw = bpx&31;
    int oh = gh*32-16+kh, ow = gw*32-16+kw;
    int ci = ks*32 + kgc*8;
    uint4 wv = make_uint4(0,0,0,0);
    if ((unsigned)oh<512u && (unsigned)ow<512u){
      const float* tp = t + (((size_t)n*HW2) + (size_t)oh*512 + ow)*64 + ci;
      float4 a = *(const float4*)tp, bq = *(const float4*)(tp+4);
      float4 sA = *(const float4*)(sc0+ci), sB = *(const float4*)(sc0+ci+4);
      float4 hA = *(const float4*)(sh0+ci), hB = *(const float4*)(sh0+ci+4);
      wv.x = pack2(sA.x*a.x+hA.x, sA.y*a.y+hA.y);
      wv.y = pack2(sA.z*a.z+hA.z, sA.w*a.w+hA.w);
      wv.z = pack2(sB.x*bq.x+hB.x, sB.y*bq.y+hB.y);
      wv.w = pack2(sB.z*bq.z+hB.z, sB.w*bq.w+hB.w);
    }
    *(uint4*)&Bp[idx*8] = wv;
  }
  __syncthreads();
  int w = tid>>6, l = tid&63, lr = l&15, kg4 = l>>4;
  int wm = w>>1, wn = w&1;
  f32x4 acc[4][4];
  #pragma unroll
  for (int m=0;m<4;m++)
    #pragma unroll
    for (int nn=0;nn<4;nn++) acc[m][nn] = (f32x4){0.f,0.f,0.f,0.f};
  #pragma unroll
  for (int ks=0;ks<2;ks++){
    bf8v aw[4], bp[4];
    #pragma unroll
    for (int m=0;m<4;m++)
      aw[m] = *(const bf8v*)&Aw[(ks*512 + (wm*64+m*16+lr)*4 + kg4)*8];
    #pragma unroll
    for (int nn=0;nn<4;nn++)
      bp[nn] = *(const bf8v*)&Bp[(ks*512 + kg4*128 + (wn*64+nn*16+lr))*8];
    #pragma unroll
    for (int m=0;m<4;m++)
      #pragma unroll
      for (int nn=0;nn<4;nn++)
        acc[m][nn] = __builtin_amdgcn_mfma_f32_16x16x32_bf16(aw[m], bp[nn], acc[m][nn], 0,0,0);
  }
  // epilogue: bias+relu, store u1 [px][128], stats
  float s1[4][4], s2[4][4];
  #pragma unroll
  for (int m=0;m<4;m++)
    #pragma unroll
    for (int j=0;j<4;j++){ s1[m][j]=0.f; s2[m][j]=0.f; }
  #pragma unroll
  for (int m=0;m<4;m++){
    int cobase = wm*64 + m*16 + kg4*4;
    float4 bb = *(const float4*)(b1 + cobase);
    #pragma unroll
    for (int nn=0;nn<4;nn++){
      int pxl = wn*64 + nn*16 + lr;
      size_t pg = (size_t)sblk*1024 + px0 + pxl;
      f32x4 v = acc[m][nn];
      float e0=fmaxf(v[0]+bb.x,0.f), e1=fmaxf(v[1]+bb.y,0.f), e2=fmaxf(v[2]+bb.z,0.f), e3=fmaxf(v[3]+bb.w,0.f);
      ushort4 st = make_ushort4(f2b(e0), f2b(e1), f2b(e2), f2b(e3));
      *(ushort4*)(u1 + pg*128 + cobase) = st;
      s1[m][0]+=e0; s1[m][1]+=e1; s1[m][2]+=e2; s1[m][3]+=e3;
      s2[m][0]+=e0*e0; s2[m][1]+=e1*e1; s2[m][2]+=e2*e2; s2[m][3]+=e3*e3;
    }
  }
  #pragma unroll
  for (int m=0;m<4;m++)
    #pragma unroll
    for (int j=0;j<4;j++){
      float a=s1[m][j], q=s2[m][j];
      a += __shfl_xor(a,1,64); q += __shfl_xor(q,1,64);
      a += __shfl_xor(a,2,64); q += __shfl_xor(q,2,64);
      a += __shfl_xor(a,4,64); q += __shfl_xor(q,4,64);
      a += __shfl_xor(a,8,64); q += __shfl_xor(q,8,64);
      if (lr==0){
        int co = wm*64 + m*16 + kg4*4 + j;
        atomicAdd(&st_s[co], a);
        atomicAdd(&st_s[128+co], q);
      }
    }
  __syncthreads();
  if (tid < 256) partials[(size_t)tid*PSTRIDE + wg] = st_s[tid];
}

// ---------- K5: bn1 + conv3x3 MFMA (tap-loop, per-block zero pad) -> u2 [px][128] bf16, stats ----------
__global__ __launch_bounds__(256) void k_conv3(const u16* __restrict__ u1,
    const u16* __restrict__ w2t, const float* __restrict__ b2,
    const float* __restrict__ sc1, const float* __restrict__ sh1,
    u16* __restrict__ u2, float* __restrict__ partials,
    const int* __restrict__ list, const int* __restrict__ count){
  int wg = blockIdx.x;
  int sblk = wg>>3, sub = wg&7;
  if (sblk >= dcnt(count)) return;
  int r0 = sub*4;
  __shared__ u16 Wlds[2][1536*8];   // [buf][(tl*128+co)*4+kg][8]
  __shared__ u16 Plds[2][816*8];    // [buf][(row*34+col)*4+kg][8]
  __shared__ float st_s[256];
  int tid = threadIdx.x;
  if (tid < 256) st_s[tid] = 0.f;
  int w = tid>>6, lane = tid&63, lr = lane&15, kg4 = lane>>4;
  int wm = w>>1, wn = w&1;

  auto stageW = [&](int s, int buf){
    int ci0 = (s/3)*32, tap0 = (s%3)*3;
    #pragma unroll
    for (int i=0;i<6;i++){
      int cidx = w*384 + i*64 + lane;
      int tl = cidx>>9, co = (cidx>>2)&127, kgc = cidx&3;
      const u16* g = w2t + (size_t)(tap0+tl)*16384 + co*128 + ci0 + kgc*8;
      gl_lds16(g, &Wlds[buf][(w*384 + i*64)*8]);
    }
  };
  auto stageP = [&](int ch, int buf){
    int ci0 = ch*32;
    #pragma unroll
    for (int i=0;i<4;i++){
      int idx = tid + i*256;
      if (idx < 816){
        int row = idx/136, rem = idx - row*136, col = rem>>2, kgc = rem&3;
        int ir = r0 + row - 1, ic = col - 1;
        uint4 wv = make_uint4(0,0,0,0);
        if ((unsigned)ir<32u && (unsigned)ic<32u){
          int cb = ci0 + kgc*8;
          uint4 raw = *(const uint4*)(u1 + ((size_t)sblk*1024 + ir*32 + ic)*128 + cb);
          float4 sA = *(const float4*)(sc1+cb), sB = *(const float4*)(sc1+cb+4);
          float4 hA = *(const float4*)(sh1+cb), hB = *(const float4*)(sh1+cb+4);
          float v0 = sA.x*b2f((u16)raw.x)+hA.x,      v1 = sA.y*b2f((u16)(raw.x>>16))+hA.y;
          float v2 = sA.z*b2f((u16)raw.y)+hA.z,      v3 = sA.w*b2f((u16)(raw.y>>16))+hA.w;
          float v4 = sB.x*b2f((u16)raw.z)+hB.x,      v5 = sB.y*b2f((u16)(raw.z>>16))+hB.y;
          float v6 = sB.z*b2f((u16)raw.w)+hB.z,      v7 = sB.w*b2f((u16)(raw.w>>16))+hB.w;
          wv.x = pack2(v0,v1); wv.y = pack2(v2,v3); wv.z = pack2(v4,v5); wv.w = pack2(v6,v7);
        }
        *(uint4*)&Plds[buf][idx*8] = wv;
      }
    }
  };

  f32x4 acc[4][4];
  #pragma unroll
  for (int m=0;m<4;m++)
    #pragma unroll
    for (int nn=0;nn<4;nn++) acc[m][nn] = (f32x4){0.f,0.f,0.f,0.f};

  stageW(0, 0);
  stageP(0, 0);
  __syncthreads();
  int step = 0;
  for (int ch=0; ch<4; ch++){
    for (int tg=0; tg<3; tg++, step++){
      int nstep = step+1;
      if (nstep < 12) stageW(nstep, nstep&1);
      int wbuf = step&1, pbuf = ch&1;
      #pragma unroll
      for (int tl=0; tl<3; tl++){
        bf8v aw[4], bp[4];
        #pragma unroll
        for (int m=0;m<4;m++)
          aw[m] = *(const bf8v*)&Wlds[wbuf][((tl*128 + wm*64+m*16+lr)*4 + kg4)*8];
        #pragma unroll
        for (int nn=0;nn<4;nn++){
          int pxl = wn*64 + nn*16 + lr;
          int rr_ = pxl>>5, cc_ = pxl&31;
          bp[nn] = *(const bf8v*)&Plds[pbuf][(((rr_+tg)*34 + (cc_+tl))*4 + kg4)*8];
        }
        #pragma unroll
        for (int m=0;m<4;m++)
          #pragma unroll
          for (int nn=0;nn<4;nn++)
            acc[m][nn] = __builtin_amdgcn_mfma_f32_16x16x32_bf16(aw[m], bp[nn], acc[m][nn], 0,0,0);
      }
      if (tg==2 && ch<3) stageP(ch+1, (ch+1)&1);
      __syncthreads();
    }
  }
  // epilogue
  float s1[4][4], s2[4][4];
  #pragma unroll
  for (int m=0;m<4;m++)
    #pragma unroll
    for (int j=0;j<4;j++){ s1[m][j]=0.f; s2[m][j]=0.f; }
  #pragma unroll
  for (int m=0;m<4;m++){
    int cobase = wm*64 + m*16 + kg4*4;
    float4 bb = *(const float4*)(b2 + cobase);
    #pragma unroll
    for (int nn=0;nn<4;nn++){
      int pxl = wn*64 + nn*16 + lr;
      size_t pg = (size_t)sblk*1024 + sub*128 + pxl;
      f32x4 v = acc[m][nn];
      float e0=fmaxf(v[0]+bb.x,0.f), e1=fmaxf(v[1]+bb.y,0.f), e2=fmaxf(v[2]+bb.z,0.f), e3=fmaxf(v[3]+bb.w,0.f);
      ushort4 st = make_ushort4(f2b(e0), f2b(e1), f2b(e2), f2b(e3));
      *(ushort4*)(u2 + pg*128 + cobase) = st;
      s1[m][0]+=e0; s1[m][1]+=e1; s1[m][2]+=e2; s1[m][3]+=e3;
      s2[m][0]+=e0*e0; s2[m][1]+=e1*e1; s2[m][2]+=e2*e2; s2[m][3]+=e3*e3;
    }
  }
  #pragma unroll
  for (int m=0;m<4;m++)
    #pragma unroll
    for (int j=0;j<4;j++){
      float a=s1[m][j], q=s2[m][j];
      a += __shfl_xor(a,1,64); q += __shfl_xor(q,1,64);
      a += __shfl_xor(a,2,64); q += __shfl_xor(q,2,64);
      a += __shfl_xor(a,4,64); q += __shfl_xor(q,4,64);
      a += __shfl_xor(a,8,64); q += __shfl_xor(q,8,64);
      if (lr==0){
        int co = wm*64 + m*16 + kg4*4 + j;
        atomicAdd(&st_s[co], a);
        atomicAdd(&st_s[128+co], q);
      }
    }
  __syncthreads();
  if (tid < 256) partials[(size_t)tid*PSTRIDE + wg] = st_s[tid];
}

// ---------- K7: conv1x1(128->64) MFMA (bn2+bias folded into w3t/bias3p) -> g [px][64] bf16, stats ----------
__global__ __launch_bounds__(256) void k_convD(const u16* __restrict__ u2,
    const u16* __restrict__ w3t, const float* __restrict__ bias3p,
    u16* __restrict__ g, float* __restrict__ partials,
    const int* __restrict__ list, const int* __restrict__ count){
  int wg = blockIdx.x;
  int sblk = wg>>3, sub = wg&7;
  if (sblk >= dcnt(count)) return;
  int px0 = sub*128;
  __shared__ u16 Aw[1024*8];     // [ks4][co64][kg4][8] : idx = ks*256+co*4+kg
  __shared__ u16 Bp[2048*8];     // [px128][sp16][8] swizzled
  __shared__ float st_s[128];
  int tid = threadIdx.x;
  if (tid < 128) st_s[tid] = 0.f;
  int w = tid>>6, lane = tid&63, lr = lane&15, kg4 = lane>>4;
  #pragma unroll
  for (int i=0;i<4;i++){
    int c = w*256 + i*64 + lane;
    int ks = c>>8, co = (c>>2)&63, kgc = c&3;
    gl_lds16(w3t + co*128 + ks*32 + kgc*8, &Aw[(w*256 + i*64)*8]);
  }
  #pragma unroll
  for (int i=0;i<8;i++){
    int c = w*512 + i*64 + lane;
    int px = c>>4, sp = c&15;
    int sl = (sp&8) | ((sp&7) ^ (px&7));     // inverse == forward (involution)
    gl_lds16(u2 + ((size_t)sblk*1024 + px0 + px)*128 + sl*8, &Bp[(w*512 + i*64)*8]);
  }
  __syncthreads();
  int wn = w;                                 // 4 waves split px: 32 each
  f32x4 acc[4][2];
  #pragma unroll
  for (int m=0;m<4;m++){ acc[m][0]=(f32x4){0,0,0,0}; acc[m][1]=(f32x4){0,0,0,0}; }
  #pragma unroll
  for (int ks=0;ks<4;ks++){
    bf8v aw[4], bp[2];
    #pragma unroll
    for (int m=0;m<4;m++)
      aw[m] = *(const bf8v*)&Aw[(ks*256 + (m*16+lr)*4 + kg4)*8];
    #pragma unroll
    for (int nn=0;nn<2;nn++){
      int pxl = wn*32 + nn*16 + lr;
      int sl = ks*4 + kg4;
      int sp = (sl&8) | ((sl&7) ^ (pxl&7));
      bp[nn] = *(const bf8v*)&Bp[(pxl*16 + sp)*8];
    }
    #pragma unroll
    for (int m=0;m<4;m++)
      #pragma unroll
      for (int nn=0;nn<2;nn++)
        acc[m][nn] = __builtin_amdgcn_mfma_f32_16x16x32_bf16(aw[m], bp[nn], acc[m][nn], 0,0,0);
  }
  float s1[4][4], s2[4][4];
  #pragma unroll
  for (int m=0;m<4;m++)
    #pragma unroll
    for (int j=0;j<4;j++){ s1[m][j]=0.f; s2[m][j]=0.f; }
  #pragma unroll
  for (int m=0;m<4;m++){
    int cobase = m*16 + kg4*4;
    float4 bb = *(const float4*)(bias3p + cobase);
    #pragma unroll
    for (int nn=0;nn<2;nn++){
      int pxl = wn*32 + nn*16 + lr;
      size_t pg = (size_t)sblk*1024 + px0 + pxl;
      f32x4 v = acc[m][nn];
      float e0=fmaxf(v[0]+bb.x,0.f), e1=fmaxf(v[1]+bb.y,0.f), e2=fmaxf(v[2]+bb.z,0.f), e3=fmaxf(v[3]+bb.w,0.f);
      ushort4 st = make_ushort4(f2b(e0), f2b(e1), f2b(e2), f2b(e3));
      *(ushort4*)(g + pg*64 + cobase) = st;
      s1[m][0]+=e0; s1[m][1]+=e1; s1[m][2]+=e2; s1[m][3]+=e3;
      s2[m][0]+=e0*e0; s2[m][1]+=e1*e1; s2[m][2]+=e2*e2; s2[m][3]+=e3*e3;
    }
  }
  #pragma unroll
  for (int m=0;m<4;m++)
    #pragma unroll
    for (int j=0;j<4;j++){
      float a=s1[m][j], q=s2[m][j];
      a += __shfl_xor(a,1,64); q += __shfl_xor(q,1,64);
      a += __shfl_xor(a,2,64); q += __shfl_xor(q,2,64);
      a += __shfl_xor(a,4,64); q += __shfl_xor(q,4,64);
      a += __shfl_xor(a,8,64); q += __shfl_xor(q,8,64);
      if (lr==0){
        int co = m*16 + kg4*4 + j;
        atomicAdd(&st_s[co], a);
        atomicAdd(&st_s[64+co], q);
      }
    }
  __syncthreads();
  if (tid < 128) partials[(size_t)tid*PSTRIDE + wg] = st_s[tid];
}

// ---------- K9: out[n][c][ph][pw] = pad(bn0(t)) + scatter(bn3(g)) ----------
__global__ __launch_bounds__(256) void k_out(const float* __restrict__ t,
    const u16* __restrict__ g, const float* __restrict__ sc0, const float* __restrict__ sh0,
    const float* __restrict__ sc3, const float* __restrict__ sh3,
    const int* __restrict__ slotmap, float* __restrict__ out){
  int pwt = blockIdx.x;        // 0..16
  int ph  = blockIdx.y;        // 0..543
  int n   = blockIdx.z;        // 0..3
  __shared__ float T[64][36];
  int tid = threadIdx.x;
  int slot = slotmap[n*289 + (ph>>5)*17 + pwt];
  int oh = ph - 16;
  #pragma unroll
  for (int s=0;s<2;s++){
    int chunk = tid + s*256;                  // 512 chunks = 32 pw x 16 cquads
    int pw_l = chunk>>4, cq = chunk&15;
    int c = cq*4;
    int ow = pwt*32 + pw_l - 16;
    float4 v = make_float4(0.f,0.f,0.f,0.f);
    if ((unsigned)oh<512u && (unsigned)ow<512u){
      float4 tv = *(const float4*)(t + (((size_t)n*HW2) + (size_t)oh*512 + ow)*64 + c);
      float4 s0 = *(const float4*)(sc0+c), h0 = *(const float4*)(sh0+c);
      v = make_float4(s0.x*tv.x+h0.x, s0.y*tv.y+h0.y, s0.z*tv.z+h0.z, s0.w*tv.w+h0.w);
    }
    if (slot >= 0){
      int kh = ph&31, kw = pw_l;
      ushort4 gv = *(const ushort4*)(g + ((size_t)slot*1024 + kh*32 + kw)*64 + c);
      float4 s3 = *(const float4*)(sc3+c), h3 = *(const float4*)(sh3+c);
      v.x += s3.x*b2f(gv.x)+h3.x; v.y += s3.y*b2f(gv.y)+h3.y;
      v.z += s3.z*b2f(gv.z)+h3.z; v.w += s3.w*b2f(gv.w)+h3.w;
    }
    T[c+0][pw_l]=v.x; T[c+1][pw_l]=v.y; T[c+2][pw_l]=v.z; T[c+3][pw_l]=v.w;
  }
  __syncthreads();
  int c = tid>>2, s2_ = tid&3;
  int pwl0 = s2_*8;
  float4 o1 = *(const float4*)&T[c][pwl0];
  float4 o2 = *(const float4*)&T[c][pwl0+4];
  float* op = out + ((size_t)(n*64+c))*295936 + (size_t)ph*544 + pwt*32 + pwl0;
  *(float4*)op = o1;
  *(float4*)(op+4) = o2;
}

// ---------- launch ----------
extern "C" void kernel_launch(void* const* d_in, const int* in_sizes, int n_in,
                              void* d_out, int out_size, void* d_ws, size_t ws_size,
                              hipStream_t stream){
  const float* x     = (const float*)d_in[0];
  const int*   mask  = (const int*)  d_in[1];
  const float* cc_w  = (const float*)d_in[2];
  const float* cc_b  = (const float*)d_in[3];
  const float* cc_g  = (const float*)d_in[4];
  const float* cc_be = (const float*)d_in[5];
  const float* w1 = (const float*)d_in[6];
  const float* b1 = (const float*)d_in[7];
  const float* g1 = (const float*)d_in[8];
  const float* be1= (const float*)d_in[9];
  const float* w2 = (const float*)d_in[10];
  const float* b2 = (const float*)d_in[11];
  const float* g2 = (const float*)d_in[12];
  const float* be2= (const float*)d_in[13];
  const float* w3 = (const float*)d_in[14];
  const float* b3 = (const float*)d_in[15];
  const float* g3 = (const float*)d_in[16];
  const float* be3= (const float*)d_in[17];
  float* out = (float*)d_out;

  char* ws = (char*)d_ws;
  int* count   = (int*)(ws + 0);
  int* slotmap = (int*)(ws + 64);
  int* list    = (int*)(ws + 4736);
  float* sc0=(float*)(ws+9472);  float* sh0=(float*)(ws+9728);
  float* sc1=(float*)(ws+9984);  float* sh1=(float*)(ws+10496);
  float* sc2=(float*)(ws+11008); float* sh2=(float*)(ws+11520);
  float* sc3=(float*)(ws+12032); float* sh3=(float*)(ws+12288);
  float* bias3p=(float*)(ws+12544);
  u16* w2t = (u16*)(ws + 32768);           // 294912 B
  u16* w3t = (u16*)(ws + 327680);          // 16384 B
  float* partials = (float*)(ws + 344064); // 256*9472*4 = 9,699,328 B
  float* tbuf = (float*)(ws + 10485760);   // 268,435,456 B
  u16* u1 = (u16*)(ws + 278921216);        // 268,435,456 B (MAXB blocks)
  u16* u2 = (u16*)(ws + 547356672);        // 268,435,456 B
  u16* gbuf = u1;                          // alias: u1 dead after conv3

  hipMemsetAsync(d_ws, 0, 32768, stream);
  k_flags<<<NBLK,256,0,stream>>>(mask, slotmap, list, count);
  k_w2prep<<<576,256,0,stream>>>(w2, w2t);
  k_cc<<<4096,256,0,stream>>>(x, cc_w, cc_b, tbuf, partials);
  k_finR<<<64,256,0,stream>>>(partials, cc_g, cc_be, sc0, sh0, 64, count, 0);
  k_conv1<<<NBLK*8,256,0,stream>>>(tbuf, w1, b1, sc0, sh0, u1, partials, list, count);
  k_finR<<<128,256,0,stream>>>(partials, g1, be1, sc1, sh1, 128, count, 1);
  k_conv3<<<NBLK*8,256,0,stream>>>(u1, w2t, b2, sc1, sh1, u2, partials, list, count);
  k_finR<<<128,256,0,stream>>>(partials, g2, be2, sc2, sh2, 128, count, 1);
  k_w3prep<<<1,64,0,stream>>>(w3, b3, sc2, sh2, w3t, bias3p);
  k_convD<<<NBLK*8,256,0,stream>>>(u2, w3t, bias3p, gbuf, partials, list, count);
  k_finR<<<64,256,0,stream>>>(partials, g3, be3, sc3, sh3, 64, count, 1);
  k_out<<<dim3(17,544,4),256,0,stream>>>(tbuf, gbuf, sc0, sh0, sc3, sh3, slotmap, out);
}